// Round 5
// baseline (167.645 us; speedup 1.0000x reference)
//
#include <hip/hip_runtime.h>
#include <math.h>

#define KS 11
#define CHUNK 33      // output rows per block = 3 x 11 (ring phases static)
#define GRIDY 16      // 16*33 = 528 >= 512; tail rows masked out of the sum
#define IMW 512
#define IMH 512

struct G11 { float g[KS]; };

// ---- shared pieces -------------------------------------------------------

#define SSIM_VERT_AND_ACC(kk)                                               \
    {                                                                       \
        float m1 = 0.f, m2 = 0.f, s11 = 0.f, s22 = 0.f, s12 = 0.f;          \
        _Pragma("unroll")                                                   \
        for (int j = 0; j < KS; ++j) {                                      \
            const float w = gw.g[j];                                        \
            m1  = fmaf(w, h0[((kk) + j) % KS], m1);                         \
            m2  = fmaf(w, h1[((kk) + j) % KS], m2);                         \
            s11 = fmaf(w, h2[((kk) + j) % KS], s11);                        \
            s22 = fmaf(w, h3[((kk) + j) % KS], s22);                        \
            s12 = fmaf(w, h4[((kk) + j) % KS], s12);                        \
        }                                                                   \
        const float mu1s = m1 * m1, mu2s = m2 * m2, mu12 = m1 * m2;         \
        const float sg1  = s11 - mu1s;                                      \
        const float sg2  = s22 - mu2s;                                      \
        const float sg12 = s12 - mu12;                                      \
        const float num = (2.f * mu12 + C1) * (2.f * sg12 + C2);            \
        const float den = (mu1s + mu2s + C1) * (sg1 + sg2 + C2);            \
        const float val = num * __builtin_amdgcn_rcpf(den);                 \
        acc += (y0 + k < IMH) ? val : 0.f;                                  \
    }

#define HCONV_BODY                                                          \
    _Pragma("unroll")                                                       \
    for (int j = 0; j < KS; ++j) {                                          \
        const float w = whj(j);                                             \
        const float wv = w * pj[j];                                         \
        const float wu = w * tj[j];                                         \
        a0 += wv; a1 += wu;                                                 \
        a2 = fmaf(wv, pj[j], a2);                                           \
        a3 = fmaf(wu, tj[j], a3);                                           \
        a4 = fmaf(wv, tj[j], a4);                                           \
    }

// ---- interior kernel: all 11 horizontal taps guaranteed in-bounds --------
// columns 64..447 (blockIdx.x 0..5). Loads are base + compile-time
// immediate offsets: no per-lane address arrays, no weight masks.
__global__ __launch_bounds__(64, 4) void ssim_col_interior(
    const float* __restrict__ pred, const float* __restrict__ target,
    float* __restrict__ partial, G11 gw)
{
    const int lane = threadIdx.x;
    const int x    = 64 + blockIdx.x * 64 + lane;   // 64..447
    const int y0   = blockIdx.y * CHUNK;
    const int bc   = blockIdx.z;
    const float* pb = pred   + (size_t)bc * (IMH * IMW) + x;
    const float* tb = target + (size_t)bc * (IMH * IMW) + x;

    float h0[KS], h1[KS], h2[KS], h3[KS], h4[KS];

#define whj(j) gw.g[j]
#define INGEST(S, YI)                                                       \
    {                                                                       \
        const int yi = (YI);                                                \
        float a0 = 0.f, a1 = 0.f, a2 = 0.f, a3 = 0.f, a4 = 0.f;             \
        if ((unsigned)yi < (unsigned)IMH) {                                 \
            const float* pr = pb + (size_t)yi * IMW;                        \
            const float* tr = tb + (size_t)yi * IMW;                        \
            float pj[KS], tj[KS];                                           \
            _Pragma("unroll")                                               \
            for (int j = 0; j < KS; ++j) { pj[j] = pr[j - 5]; tj[j] = tr[j - 5]; } \
            HCONV_BODY                                                      \
        }                                                                   \
        h0[S] = a0; h1[S] = a1; h2[S] = a2; h3[S] = a3; h4[S] = a4;         \
    }

    #pragma unroll
    for (int i = 0; i < 10; ++i) {
        INGEST(i, y0 - 5 + i)
    }

    const float C1 = 1e-4f, C2 = 9e-4f;
    float acc = 0.f;
    for (int k0 = 0; k0 < CHUNK; k0 += KS) {
        #pragma unroll
        for (int kk = 0; kk < KS; ++kk) {
            const int k = k0 + kk;
            INGEST((kk + 10) % KS, y0 + k + 5)
            SSIM_VERT_AND_ACC(kk)
        }
    }
#undef INGEST
#undef whj

    #pragma unroll
    for (int off = 32; off > 0; off >>= 1) acc += __shfl_down(acc, off, 64);
    if (lane == 0) atomicAdd(partial, acc);
}

// ---- edge kernel: columns 0..63 and 448..511 -----------------------------
// clamped per-lane byte offsets + pre-masked weights (zero-pad semantics).
__global__ __launch_bounds__(64, 4) void ssim_col_edge(
    const float* __restrict__ pred, const float* __restrict__ target,
    float* __restrict__ partial, G11 gw)
{
    const int lane = threadIdx.x;
    const int x    = blockIdx.x * 448 + lane;       // bx0 -> 0..63, bx1 -> 448..511
    const int y0   = blockIdx.y * CHUNK;
    const int bc   = blockIdx.z;
    const float* pimg = pred   + (size_t)bc * (IMH * IMW);
    const float* timg = target + (size_t)bc * (IMH * IMW);

    int   voff[KS];
    float wh[KS];
    #pragma unroll
    for (int j = 0; j < KS; ++j) {
        const int cx = x - 5 + j;
        const int ok = (cx >= 0 && cx < IMW);
        const int cc = cx < 0 ? 0 : (cx >= IMW ? IMW - 1 : cx);
        voff[j] = cc * 4;
        wh[j]   = ok ? gw.g[j] : 0.f;
    }

    float h0[KS], h1[KS], h2[KS], h3[KS], h4[KS];

#define whj(j) wh[j]
#define INGEST(S, YI)                                                       \
    {                                                                       \
        const int yi = (YI);                                                \
        float a0 = 0.f, a1 = 0.f, a2 = 0.f, a3 = 0.f, a4 = 0.f;             \
        if ((unsigned)yi < (unsigned)IMH) {                                 \
            const char* prow = (const char*)(pimg + (size_t)yi * IMW);      \
            const char* trow = (const char*)(timg + (size_t)yi * IMW);      \
            float pj[KS], tj[KS];                                           \
            _Pragma("unroll")                                               \
            for (int j = 0; j < KS; ++j) {                                  \
                pj[j] = *(const float*)(prow + voff[j]);                    \
                tj[j] = *(const float*)(trow + voff[j]);                    \
            }                                                               \
            HCONV_BODY                                                      \
        }                                                                   \
        h0[S] = a0; h1[S] = a1; h2[S] = a2; h3[S] = a3; h4[S] = a4;         \
    }

    #pragma unroll
    for (int i = 0; i < 10; ++i) {
        INGEST(i, y0 - 5 + i)
    }

    const float C1 = 1e-4f, C2 = 9e-4f;
    float acc = 0.f;
    for (int k0 = 0; k0 < CHUNK; k0 += KS) {
        #pragma unroll
        for (int kk = 0; kk < KS; ++kk) {
            const int k = k0 + kk;
            INGEST((kk + 10) % KS, y0 + k + 5)
            SSIM_VERT_AND_ACC(kk)
        }
    }
#undef INGEST
#undef whj

    #pragma unroll
    for (int off = 32; off > 0; off >>= 1) acc += __shfl_down(acc, off, 64);
    if (lane == 0) atomicAdd(partial, acc);
}

__global__ void ssim_final_kernel(const float* __restrict__ partial,
                                  float* __restrict__ out, float invN)
{
    out[0] = 1.f - partial[0] * invN;
}

extern "C" void kernel_launch(void* const* d_in, const int* in_sizes, int n_in,
                              void* d_out, int out_size, void* d_ws, size_t ws_size,
                              hipStream_t stream) {
    const float* pred   = (const float*)d_in[0];
    const float* target = (const float*)d_in[1];
    float* out = (float*)d_out;
    float* partial = (float*)d_ws;

    const int B = 16, C = 3;
    const float invN = 1.0f / ((float)B * C * IMH * IMW);

    // separable 1-D Gaussian, same formula as reference (sigma=1.5, 11 taps)
    G11 gw;
    {
        float s = 0.f;
        for (int i = 0; i < KS; ++i) {
            double e = exp(-((double)((i - 5) * (i - 5))) / (2.0 * 1.5 * 1.5));
            gw.g[i] = (float)e;
            s += gw.g[i];
        }
        for (int i = 0; i < KS; ++i) gw.g[i] /= s;
    }

    hipMemsetAsync(partial, 0, sizeof(float), stream);

    dim3 block(64);
    dim3 gi(6, GRIDY, B * C);   // interior: columns 64..447
    dim3 ge(2, GRIDY, B * C);   // edge: columns 0..63 and 448..511
    ssim_col_interior<<<gi, block, 0, stream>>>(pred, target, partial, gw);
    ssim_col_edge<<<ge, block, 0, stream>>>(pred, target, partial, gw);
    ssim_final_kernel<<<1, 1, 0, stream>>>(partial, out, invN);
}

// Round 6
// 99.766 us; speedup vs baseline: 1.6804x; 1.6804x over previous
//
#include <hip/hip_runtime.h>
#include <math.h>

#define KS 11
#define CHUNK 33      // output rows per block = 3 x 11 (ring phases static)
#define GRIDY 16      // 16*33 = 528 >= 512; tail rows masked out of the sum
#define IMW 512
#define IMH 512

struct G11 { float g[KS]; };

typedef int v4i __attribute__((ext_vector_type(4)));

// CK-style direct binding to the raw buffer load intrinsic: compiler tracks
// the load (auto waitcnt), folds constant voffset adds into the 12-bit imm.
__device__ float
raw_buf_load_f32(v4i srsrc, int voffset, int soffset, int aux)
    __asm("llvm.amdgcn.raw.buffer.load.f32");

// SRD over ONE image row: num_records = IMW*4 bytes, stride 0.
// OOB lanes (voffset < 0 treated as huge unsigned, or >= IMW*4) return 0 —
// exactly the reference conv's zero-padding, at zero VALU cost.
__device__ inline v4i make_row_srd(const float* row) {
    union { const float* p; unsigned u[2]; } a; a.p = row;
    v4i r;
    r.x = (int)a.u[0];
    r.y = (int)a.u[1];
    r.z = IMW * 4;          // num_records (bytes, stride==0)
    r.w = 0x00020000;       // raw untyped dword access
    return r;
}

// Each thread owns one output column x and streams CHUNK rows downward.
// 11-deep register ring of the 5 horizontal-conv quantities; every ring
// index is a compile-time constant (phase trick, CHUNK % 11 == 0).
__global__ __launch_bounds__(256, 1) void ssim_col_kernel(
    const float* __restrict__ pred, const float* __restrict__ target,
    float* __restrict__ partial, G11 gw)
{
    const int tid = threadIdx.x;
    const int x   = blockIdx.x * 256 + tid;       // output column, 0..511
    const int y0  = blockIdx.y * CHUNK;           // first output row
    const int bc  = blockIdx.z;
    const float* pimg = pred   + (size_t)bc * (IMH * IMW);
    const float* timg = target + (size_t)bc * (IMH * IMW);

    // single per-lane byte offset of the leftmost tap (may be negative: OOB->0)
    const int vx = (x - 5) * 4;

    // ring of horizontal conv results (5 quantities x 11 rows)
    float h0[KS], h1[KS], h2[KS], h3[KS], h4[KS];

    // Ingest input row YI into ring slot S (S is a compile-time constant
    // at every expansion; YI may be a runtime value, wave-uniform).
#define INGEST(S, YI)                                                       \
    {                                                                       \
        const int yi = (YI);                                                \
        float a0 = 0.f, a1 = 0.f, a2 = 0.f, a3 = 0.f, a4 = 0.f;             \
        if ((unsigned)yi < (unsigned)IMH) {                                 \
            const v4i ps = make_row_srd(pimg + (size_t)yi * IMW);           \
            const v4i ts = make_row_srd(timg + (size_t)yi * IMW);           \
            float pj[KS], tj[KS];                                           \
            _Pragma("unroll")                                               \
            for (int j = 0; j < KS; ++j) {                                  \
                pj[j] = raw_buf_load_f32(ps, vx + 4 * j, 0, 0);             \
                tj[j] = raw_buf_load_f32(ts, vx + 4 * j, 0, 0);             \
            }                                                               \
            _Pragma("unroll")                                               \
            for (int j = 0; j < KS; ++j) {                                  \
                const float w = gw.g[j];                                    \
                const float wv = w * pj[j];                                 \
                const float wu = w * tj[j];                                 \
                a0 += wv; a1 += wu;                                         \
                a2 = fmaf(wv, pj[j], a2);                                   \
                a3 = fmaf(wu, tj[j], a3);                                   \
                a4 = fmaf(wv, tj[j], a4);                                   \
            }                                                               \
        }                                                                   \
        h0[S] = a0; h1[S] = a1; h2[S] = a2; h3[S] = a3; h4[S] = a4;         \
    }

    // Prologue: fill slots 0..9 with input rows y0-5 .. y0+4.
    #pragma unroll
    for (int i = 0; i < 10; ++i) {
        INGEST(i, y0 - 5 + i)
    }

    const float C1 = 1e-4f, C2 = 9e-4f;
    float acc = 0.f;

    // Main: output row y = y0+k0+kk; ingest input row y+5 into slot
    // (kk+10)%11; vertical tap j reads slot (kk+j)%11. k0 is a multiple
    // of 11, so all slots depend only on kk (compile-time).
    for (int k0 = 0; k0 < CHUNK; k0 += KS) {
        #pragma unroll
        for (int kk = 0; kk < KS; ++kk) {
            const int k = k0 + kk;
            INGEST((kk + 10) % KS, y0 + k + 5)

            float m1 = 0.f, m2 = 0.f, s11 = 0.f, s22 = 0.f, s12 = 0.f;
            #pragma unroll
            for (int j = 0; j < KS; ++j) {
                const float w = gw.g[j];
                m1  = fmaf(w, h0[(kk + j) % KS], m1);
                m2  = fmaf(w, h1[(kk + j) % KS], m2);
                s11 = fmaf(w, h2[(kk + j) % KS], s11);
                s22 = fmaf(w, h3[(kk + j) % KS], s22);
                s12 = fmaf(w, h4[(kk + j) % KS], s12);
            }
            const float mu1s = m1 * m1, mu2s = m2 * m2, mu12 = m1 * m2;
            const float sg1  = s11 - mu1s;
            const float sg2  = s22 - mu2s;
            const float sg12 = s12 - mu12;
            const float num = (2.f * mu12 + C1) * (2.f * sg12 + C2);
            const float den = (mu1s + mu2s + C1) * (sg1 + sg2 + C2);
            const float val = num * __builtin_amdgcn_rcpf(den);
            // mask output rows beyond the image (block y=15 covers 495..527)
            acc += (y0 + k < IMH) ? val : 0.f;
        }
    }
#undef INGEST

    // Block reduction: wave shfl, then cross-wave via tiny LDS.
    __shared__ float wsum[4];
    #pragma unroll
    for (int off = 32; off > 0; off >>= 1) acc += __shfl_down(acc, off, 64);
    const int wid = tid >> 6, lane = tid & 63;
    if (lane == 0) wsum[wid] = acc;
    __syncthreads();
    if (tid == 0) {
        atomicAdd(partial, wsum[0] + wsum[1] + wsum[2] + wsum[3]);
    }
}

__global__ void ssim_final_kernel(const float* __restrict__ partial,
                                  float* __restrict__ out, float invN)
{
    out[0] = 1.f - partial[0] * invN;
}

extern "C" void kernel_launch(void* const* d_in, const int* in_sizes, int n_in,
                              void* d_out, int out_size, void* d_ws, size_t ws_size,
                              hipStream_t stream) {
    const float* pred   = (const float*)d_in[0];
    const float* target = (const float*)d_in[1];
    float* out = (float*)d_out;
    float* partial = (float*)d_ws;

    const int B = 16, C = 3;
    const float invN = 1.0f / ((float)B * C * IMH * IMW);

    // separable 1-D Gaussian, same formula as reference (sigma=1.5, 11 taps)
    G11 gw;
    {
        float s = 0.f;
        for (int i = 0; i < KS; ++i) {
            double e = exp(-((double)((i - 5) * (i - 5))) / (2.0 * 1.5 * 1.5));
            gw.g[i] = (float)e;
            s += gw.g[i];
        }
        for (int i = 0; i < KS; ++i) gw.g[i] /= s;
    }

    hipMemsetAsync(partial, 0, sizeof(float), stream);

    dim3 grid(IMW / 256, GRIDY, B * C);   // 2 x 16 x 48 = 1536 blocks
    dim3 block(256);
    ssim_col_kernel<<<grid, block, 0, stream>>>(pred, target, partial, gw);
    ssim_final_kernel<<<1, 1, 0, stream>>>(partial, out, invN);
}

// Round 7
// 92.588 us; speedup vs baseline: 1.8107x; 1.0775x over previous
//
#include <hip/hip_runtime.h>
#include <math.h>

#define KS 11
#define CHUNK 55      // output rows per block = 5 x 11 (ring phases static)
#define GRIDY 10      // 10*55 = 550 >= 512; tail rows masked out of the sum
#define IMW 512
#define IMH 512

struct G11 { float g[KS]; };

typedef int   v4i __attribute__((ext_vector_type(4)));
typedef float f2  __attribute__((ext_vector_type(2)));

// CK-style direct binding to the raw buffer load intrinsic: compiler tracks
// the load (auto waitcnt), folds constant voffset adds into the 12-bit imm.
__device__ float
raw_buf_load_f32(v4i srsrc, int voffset, int soffset, int aux)
    __asm("llvm.amdgcn.raw.buffer.load.f32");

// SRD over ONE image row: num_records = IMW*4 bytes, stride 0.
// OOB lanes (voffset < 0 treated as huge unsigned, or >= IMW*4) return 0 —
// exactly the reference conv's zero-padding, at zero VALU cost.
__device__ inline v4i make_row_srd(const float* row) {
    union { const float* p; unsigned u[2]; } a; a.p = row;
    v4i r;
    r.x = (int)a.u[0];
    r.y = (int)a.u[1];
    r.z = IMW * 4;          // num_records (bytes, stride==0)
    r.w = 0x00020000;       // raw untyped dword access
    return r;
}

// Each thread owns one output column x and streams CHUNK rows downward.
// pred/target are packed as {p,t} float2 lanes so the twin conv chains
// compile to packed fp32 (v_pk_*). 11-deep register ring of the
// horizontal-conv quantities; every ring index is compile-time constant.
__global__ __launch_bounds__(256, 1) void ssim_col_kernel(
    const float* __restrict__ pred, const float* __restrict__ target,
    float* __restrict__ partial, G11 gw)
{
    const int tid = threadIdx.x;
    const int x   = blockIdx.x * 256 + tid;       // output column, 0..511
    const int y0  = blockIdx.y * CHUNK;           // first output row
    const int bc  = blockIdx.z;
    const float* pimg = pred   + (size_t)bc * (IMH * IMW);
    const float* timg = target + (size_t)bc * (IMH * IMW);

    // single per-lane byte offset of the leftmost tap (may be negative: OOB->0)
    const int vx = (x - 5) * 4;

    // ring: hA = {mu1-acc, mu2-acc}, hB = {E[p^2]-acc, E[t^2]-acc}, hc = E[pt]-acc
    f2    hA[KS], hB[KS];
    float hc[KS];

    // Ingest input row YI into ring slot S (S compile-time constant).
#define INGEST(S, YI)                                                       \
    {                                                                       \
        const int yi = (YI);                                                \
        f2 A = {0.f, 0.f}, Bq = {0.f, 0.f};                                 \
        float c4 = 0.f;                                                     \
        if ((unsigned)yi < (unsigned)IMH) {                                 \
            const v4i ps = make_row_srd(pimg + (size_t)yi * IMW);           \
            const v4i ts = make_row_srd(timg + (size_t)yi * IMW);           \
            f2 pt[KS];                                                      \
            _Pragma("unroll")                                               \
            for (int j = 0; j < KS; ++j) {                                  \
                pt[j].x = raw_buf_load_f32(ps, vx + 4 * j, 0, 0);           \
                pt[j].y = raw_buf_load_f32(ts, vx + 4 * j, 0, 0);           \
            }                                                               \
            _Pragma("unroll")                                               \
            for (int j = 0; j < KS; ++j) {                                  \
                const f2 w2 = {gw.g[j], gw.g[j]};                           \
                const f2 wv = w2 * pt[j];          /* {w p, w t} */         \
                A  = A + wv;                                                \
                Bq = __builtin_elementwise_fma(wv, pt[j], Bq);              \
                c4 = fmaf(wv.x, pt[j].y, c4);      /* w p t */              \
            }                                                               \
        }                                                                   \
        hA[S] = A; hB[S] = Bq; hc[S] = c4;                                  \
    }

    // Prologue: fill slots 0..9 with input rows y0-5 .. y0+4.
    #pragma unroll
    for (int i = 0; i < 10; ++i) {
        INGEST(i, y0 - 5 + i)
    }

    const float C1 = 1e-4f, C2 = 9e-4f;
    float acc = 0.f;

    // Main: output row y = y0+k0+kk; ingest input row y+5 into slot
    // (kk+10)%11; vertical tap j reads slot (kk+j)%11. k0 is a multiple
    // of 11, so all slots depend only on kk (compile-time).
    for (int k0 = 0; k0 < CHUNK; k0 += KS) {
        #pragma unroll
        for (int kk = 0; kk < KS; ++kk) {
            const int k = k0 + kk;
            INGEST((kk + 10) % KS, y0 + k + 5)

            f2 M = {0.f, 0.f}, S2 = {0.f, 0.f};
            float s12 = 0.f;
            #pragma unroll
            for (int j = 0; j < KS; ++j) {
                const f2 w2 = {gw.g[j], gw.g[j]};
                M   = __builtin_elementwise_fma(w2, hA[(kk + j) % KS], M);
                S2  = __builtin_elementwise_fma(w2, hB[(kk + j) % KS], S2);
                s12 = fmaf(gw.g[j], hc[(kk + j) % KS], s12);
            }
            const float m1 = M.x, m2 = M.y;
            const float mu1s = m1 * m1, mu2s = m2 * m2, mu12 = m1 * m2;
            const float sg1  = S2.x - mu1s;
            const float sg2  = S2.y - mu2s;
            const float sg12 = s12 - mu12;
            const float num = (2.f * mu12 + C1) * (2.f * sg12 + C2);
            const float den = (mu1s + mu2s + C1) * (sg1 + sg2 + C2);
            const float val = num * __builtin_amdgcn_rcpf(den);
            // mask output rows beyond the image (block y=9 covers 495..549)
            acc += (y0 + k < IMH) ? val : 0.f;
        }
    }
#undef INGEST

    // Block reduction: wave shfl, then cross-wave via tiny LDS.
    __shared__ float wsum[4];
    #pragma unroll
    for (int off = 32; off > 0; off >>= 1) acc += __shfl_down(acc, off, 64);
    const int wid = tid >> 6, lane = tid & 63;
    if (lane == 0) wsum[wid] = acc;
    __syncthreads();
    if (tid == 0) {
        atomicAdd(partial, wsum[0] + wsum[1] + wsum[2] + wsum[3]);
    }
}

__global__ void ssim_final_kernel(const float* __restrict__ partial,
                                  float* __restrict__ out, float invN)
{
    out[0] = 1.f - partial[0] * invN;
}

extern "C" void kernel_launch(void* const* d_in, const int* in_sizes, int n_in,
                              void* d_out, int out_size, void* d_ws, size_t ws_size,
                              hipStream_t stream) {
    const float* pred   = (const float*)d_in[0];
    const float* target = (const float*)d_in[1];
    float* out = (float*)d_out;
    float* partial = (float*)d_ws;

    const int B = 16, C = 3;
    const float invN = 1.0f / ((float)B * C * IMH * IMW);

    // separable 1-D Gaussian, same formula as reference (sigma=1.5, 11 taps)
    G11 gw;
    {
        float s = 0.f;
        for (int i = 0; i < KS; ++i) {
            double e = exp(-((double)((i - 5) * (i - 5))) / (2.0 * 1.5 * 1.5));
            gw.g[i] = (float)e;
            s += gw.g[i];
        }
        for (int i = 0; i < KS; ++i) gw.g[i] /= s;
    }

    hipMemsetAsync(partial, 0, sizeof(float), stream);

    dim3 grid(IMW / 256, GRIDY, B * C);   // 2 x 10 x 48 = 960 blocks
    dim3 block(256);
    ssim_col_kernel<<<grid, block, 0, stream>>>(pred, target, partial, gw);
    ssim_final_kernel<<<1, 1, 0, stream>>>(partial, out, invN);
}